// Round 2
// baseline (640.503 us; speedup 1.0000x reference)
//
#include <hip/hip_runtime.h>
#include <hip/hip_bf16.h>
#include <stdint.h>

// RBF_euclidean: out[N,128] = P @ coeffs, P[i,g] = exp(-d2(x_i,grid_g)*ln2/w^2)
// Round 2 design:
//  - Separable RBF: p = e0[i]*e1[j]*e2[k2]; axis2 padded 12->16 (K'=2304) so a
//    32-wide MFMA chunk = exactly 2 (i,j) pairs; kp = c*32 + g4*8 + b is LINEAR.
//  - prep_coeffs emits B image in fragment order [kp>>3][col][kp&7] (f16 hi/lo)
//    -> staging is a pure linear copy (no swizzle, no OOB), MFMA B-read is
//    g4*2048 + col*16: consecutive 16B slots per 16-lane phase, conflict-free.
//  - 3-pass f16 split: acc += Ah*Bh + Al*Bh + Ah*Bl (~21-bit effective mantissa).
//  - BM=128, 4 waves in 2x2: each wave 64 rows x 64 cols (4 m-sub x 4 n-sub).
//    MFMA/chunk/CU = 192*4.85 = 931 cyc vs LDS 576 cyc vs VALU 272 -> MFMA-bound.

typedef _Float16 f16;
typedef _Float16 f16x8 __attribute__((ext_vector_type(8)));
typedef float f32x4 __attribute__((ext_vector_type(4)));

#define LN2F 0.69314718f
#define LOG2E 1.4426950408889634f

#define KP 2304      // 12*12*16 (axis2 padded to 16)
#define CD 128       // codomain dim
#define CHUNKS 72    // KP/32
#define BM 128       // rows per block

// ---------- prep: split coeffs f16 hi/lo, emit fragment-ordered image ----------
// image layout: idx = ((kp>>3)*CD + col)*8 + (kp&7); kp = i*192 + j*16 + k2 (k2 padded to 16)
__global__ void prep_coeffs(const float* __restrict__ coeffs,
                            f16* __restrict__ ch, f16* __restrict__ cl) {
  int kp  = blockIdx.x * 2 + (threadIdx.x >> 7);   // 0..2303
  int col = threadIdx.x & 127;
  int i   = kp / 192;
  int rem = kp - i * 192;
  int j   = rem >> 4;
  int k2  = rem & 15;
  float v = 0.f;
  if (k2 < 12) v = coeffs[(size_t)((i * 12 + j) * 12 + k2) * CD + col];
  f16 h = (f16)v;
  f16 l = (f16)(v - (float)h);
  size_t idx = ((size_t)(kp >> 3) * CD + col) * 8 + (kp & 7);
  ch[idx] = h;
  cl[idx] = l;
}

// ---------- main GEMM ----------
__global__ __launch_bounds__(256) void rbf_gemm(
    const float* __restrict__ x, const float* __restrict__ grid,
    const float* __restrict__ width,
    const f16* __restrict__ ch, const f16* __restrict__ cl,
    float* __restrict__ out, int N) {
  __shared__ float E0[12 * BM];
  __shared__ float E1[12 * BM];
  __shared__ float E2[BM * 16];
  __shared__ float GAX[3 * 16];
  __shared__ f16 Bh[2][32 * CD];   // linear fragment image, 8KB each
  __shared__ f16 Bl[2][32 * CD];

  const int t = threadIdx.x;
  const int rbase = blockIdx.x * BM;

  // axis values of the separable grid
  if (t < 48) {
    int d = t >> 4, k = t & 15;
    float g = 0.f;
    if (k < 12) {
      if (d == 0)      g = grid[(k * 144) * 3 + 0];
      else if (d == 1) g = grid[(k * 12) * 3 + 1];
      else             g = grid[k * 3 + 2];
    }
    GAX[d * 16 + k] = g;
  }
  __syncthreads();

  const float w = width[0];
  const float s2 = (LN2F * LOG2E) / (w * w);   // p = 2^(-d2*s2)

  // per-axis exp tables for this block's rows
  for (int v = t; v < 40 * BM; v += 256) {
    int a = v >> 7;           // 0..39
    int r = v & (BM - 1);
    int rr = rbase + r; if (rr >= N) rr = N - 1;
    if (a < 12) {
      float dx = x[(size_t)rr * 3 + 0] - GAX[a];
      E0[a * BM + r] = exp2f(-dx * dx * s2);
    } else if (a < 24) {
      int k = a - 12;
      float dx = x[(size_t)rr * 3 + 1] - GAX[16 + k];
      E1[k * BM + r] = exp2f(-dx * dx * s2);
    } else {
      int k = a - 24;
      float e = 0.f;
      if (k < 12) {
        float dx = x[(size_t)rr * 3 + 2] - GAX[32 + k];
        e = exp2f(-dx * dx * s2);
      }
      E2[r * 16 + k] = e;      // pad entries = 0 -> p=0 on padded K rows
    }
  }

  const int lane = t & 63;
  const int wv   = t >> 6;          // wave 0..3
  const int wvr  = wv >> 1;         // wave row group (0..1) -> rows wvr*64..+64
  const int wvc  = wv & 1;          // wave col group (0..1) -> cols wvc*64..+64
  const int l15  = lane & 15;
  const int g4   = lane >> 4;
  const int k2b  = (g4 & 1) * 8;    // lane's fixed k2 base
  const int pairSel = g4 >> 1;

  // ---- staging: pure linear copy (image is already fragment-ordered) ----
  uint4 vh[2], vl[2];
  auto stageLoad = [&](int c) {
    const char* bh = (const char*)ch + (size_t)c * 8192;
    const char* bl = (const char*)cl + (size_t)c * 8192;
#pragma unroll
    for (int r = 0; r < 2; ++r) {
      int L = r * 4096 + t * 16;
      vh[r] = *(const uint4*)(bh + L);
      vl[r] = *(const uint4*)(bl + L);
    }
  };
  auto stageWrite = [&](int d) {
#pragma unroll
    for (int r = 0; r < 2; ++r) {
      int L = r * 4096 + t * 16;
      *(uint4*)((char*)&Bh[d][0] + L) = vh[r];
      *(uint4*)((char*)&Bl[d][0] + L) = vl[r];
    }
  };

  stageLoad(0);
  stageWrite(0);
  __syncthreads();   // covers E tables + chunk-0 staging

  // lane-resident e2 values: 8 per row, 4 m-subtiles
  float e2v[4][8];
#pragma unroll
  for (int mi = 0; mi < 4; ++mi) {
    int rl = wvr * 64 + mi * 16 + l15;
    f32x4 a = *(const f32x4*)&E2[rl * 16 + k2b];
    f32x4 b = *(const f32x4*)&E2[rl * 16 + k2b + 4];
    e2v[mi][0] = a.x; e2v[mi][1] = a.y; e2v[mi][2] = a.z; e2v[mi][3] = a.w;
    e2v[mi][4] = b.x; e2v[mi][5] = b.y; e2v[mi][6] = b.z; e2v[mi][7] = b.w;
  }

  f32x4 acc[4][4];
#pragma unroll
  for (int mi = 0; mi < 4; ++mi)
#pragma unroll
    for (int nn = 0; nn < 4; ++nn) acc[mi][nn] = (f32x4){0.f, 0.f, 0.f, 0.f};

  for (int c = 0; c < CHUNKS; ++c) {
    int cn = c + 1; if (cn == CHUNKS) cn = 0;
    stageLoad(cn);              // issue next-chunk global loads early
    const int buf = c & 1;

    // this chunk's (i,j) pair (per half-wave) and A fragments
    int pair = 2 * c + pairSel;
    int i = (pair * 683) >> 13;   // /12, valid for pair<144
    int j = pair - i * 12;

    f16x8 ah[4], al[4];
#pragma unroll
    for (int mi = 0; mi < 4; ++mi) {
      int rl = wvr * 64 + mi * 16 + l15;
      float e01 = E0[i * BM + rl] * E1[j * BM + rl];
#pragma unroll
      for (int b = 0; b < 8; ++b) {
        float p = e01 * e2v[mi][b];
        f16 h = (f16)p;
        ah[mi][b] = h;
        al[mi][b] = (f16)(p - (float)h);
      }
    }

    const char* bhBase = (const char*)&Bh[buf][0];
    const char* blBase = (const char*)&Bl[buf][0];
#pragma unroll
    for (int nn = 0; nn < 4; ++nn) {
      int off = g4 * 2048 + (wvc * 64 + nn * 16 + l15) * 16;
      f16x8 bh = *(const f16x8*)(bhBase + off);
      f16x8 bl = *(const f16x8*)(blBase + off);
#pragma unroll
      for (int mi = 0; mi < 4; ++mi) {
        acc[mi][nn] = __builtin_amdgcn_mfma_f32_16x16x32_f16(ah[mi], bh, acc[mi][nn], 0, 0, 0);
        acc[mi][nn] = __builtin_amdgcn_mfma_f32_16x16x32_f16(al[mi], bh, acc[mi][nn], 0, 0, 0);
        acc[mi][nn] = __builtin_amdgcn_mfma_f32_16x16x32_f16(ah[mi], bl, acc[mi][nn], 0, 0, 0);
      }
    }

    stageWrite(buf ^ 1);   // write next chunk into the other buffer
    __syncthreads();
  }

  // epilogue: D layout col=lane&15, row=(lane>>4)*4+reg
#pragma unroll
  for (int mi = 0; mi < 4; ++mi)
#pragma unroll
    for (int nn = 0; nn < 4; ++nn)
#pragma unroll
      for (int q = 0; q < 4; ++q) {
        int row = rbase + wvr * 64 + mi * 16 + g4 * 4 + q;
        int col = wvc * 64 + nn * 16 + l15;
        if (row < N) out[(size_t)row * CD + col] = acc[mi][nn][q];
      }
}

// ---------- slow-but-correct fallback (only if ws is too small) ----------
__global__ void rbf_fallback(const float* __restrict__ x, const float* __restrict__ grid,
                             const float* __restrict__ coeffs, const float* __restrict__ width,
                             float* __restrict__ out, int N) {
  int row = blockIdx.x;
  int col = threadIdx.x;
  if (row >= N) return;
  float x0 = x[(size_t)row * 3 + 0];
  float x1 = x[(size_t)row * 3 + 1];
  float x2 = x[(size_t)row * 3 + 2];
  float w = width[0];
  float s2 = (LN2F * LOG2E) / (w * w);
  float acc = 0.f;
  for (int g = 0; g < 1728; ++g) {
    float d0 = x0 - grid[g * 3 + 0];
    float d1 = x1 - grid[g * 3 + 1];
    float d2 = x2 - grid[g * 3 + 2];
    float p = exp2f(-(d0 * d0 + d1 * d1 + d2 * d2) * s2);
    acc += p * coeffs[(size_t)g * CD + col];
  }
  out[(size_t)row * CD + col] = acc;
}

extern "C" void kernel_launch(void* const* d_in, const int* in_sizes, int n_in,
                              void* d_out, int out_size, void* d_ws, size_t ws_size,
                              hipStream_t stream) {
  const float* x      = (const float*)d_in[0];
  const float* grid   = (const float*)d_in[1];
  const float* coeffs = (const float*)d_in[2];
  const float* width  = (const float*)d_in[3];
  float* out = (float*)d_out;
  int N = in_sizes[0] / 3;

  size_t need = (size_t)2 * CD * KP * sizeof(f16);   // ~1.13 MB
  if (ws_size >= need) {
    f16* ch = (f16*)d_ws;
    f16* cl = ch + (size_t)CD * KP;
    hipLaunchKernelGGL(prep_coeffs, dim3(KP / 2), dim3(256), 0, stream,
                       coeffs, ch, cl);
    int nb = (N + BM - 1) / BM;
    hipLaunchKernelGGL(rbf_gemm, dim3(nb), dim3(256), 0, stream,
                       x, grid, width, ch, cl, out, N);
  } else {
    hipLaunchKernelGGL(rbf_fallback, dim3(N), dim3(CD), 0, stream,
                       x, grid, coeffs, width, out, N);
  }
}

// Round 3
// 356.921 us; speedup vs baseline: 1.7945x; 1.7945x over previous
//
#include <hip/hip_runtime.h>
#include <stdint.h>

// RBF_euclidean: out[N,128] = P @ coeffs, P[i,g] = exp(-d2(x_i,grid_g)*ln2/w^2)
// Round 3: same math as round 2 (passed, absmax 0.0508), new schedule:
//  - B staged via global_load_lds width=16 (image is linear fragment order),
//    issued right after loop-top __syncthreads, consumed at the NEXT sync
//    -> full-chunk latency hiding, no reg round-trip, no ds_writes for B.
//  - One __syncthreads per chunk; double-buffered LDS (explicit parity bodies).
//  - E tables built 1 thread/row (3 coalesced x loads, 40 exp2f), analytic axes.
//  - s_setprio(1) around the MFMA cluster (independent-block regime).

typedef _Float16 f16;
typedef _Float16 f16x8 __attribute__((ext_vector_type(8)));
typedef float f32x4 __attribute__((ext_vector_type(4)));

#define LN2F 0.69314718f
#define LOG2E 1.4426950408889634f

#define KP 2304      // 12*12*16 (axis2 padded to 16)
#define CD 128       // codomain dim
#define CHUNKS 72    // KP/32
#define BM 128       // rows per block

// ---------- prep: split coeffs f16 hi/lo, emit fragment-ordered image ----------
// image layout: idx = ((kp>>3)*CD + col)*8 + (kp&7); kp = i*192 + j*16 + k2 (k2 padded to 16)
__global__ void prep_coeffs(const float* __restrict__ coeffs,
                            f16* __restrict__ ch, f16* __restrict__ cl) {
  int kp  = blockIdx.x * 2 + (threadIdx.x >> 7);   // 0..2303
  int col = threadIdx.x & 127;
  int i   = kp / 192;
  int rem = kp - i * 192;
  int j   = rem >> 4;
  int k2  = rem & 15;
  float v = 0.f;
  if (k2 < 12) v = coeffs[(size_t)((i * 12 + j) * 12 + k2) * CD + col];
  f16 h = (f16)v;
  f16 l = (f16)(v - (float)h);
  size_t idx = ((size_t)(kp >> 3) * CD + col) * 8 + (kp & 7);
  ch[idx] = h;
  cl[idx] = l;
}

__device__ __forceinline__ void gload16(const void* g, void* l) {
  __builtin_amdgcn_global_load_lds(
      (const __attribute__((address_space(1))) void*)g,
      (__attribute__((address_space(3))) void*)l, 16, 0, 0);
}

// ---------- main GEMM ----------
__global__ __launch_bounds__(256) void rbf_gemm(
    const float* __restrict__ x, const float* __restrict__ grid,
    const float* __restrict__ width,
    const f16* __restrict__ ch, const f16* __restrict__ cl,
    float* __restrict__ out, int N) {
  __shared__ float E0[12 * BM];    // 6 KB
  __shared__ float E1[12 * BM];    // 6 KB
  __shared__ float E2[BM * 16];    // 8 KB
  __shared__ f16 Bh[2][32 * CD];   // 16 KB (linear fragment image, dbuf)
  __shared__ f16 Bl[2][32 * CD];   // 16 KB

  const int t = threadIdx.x;
  const int lane = t & 63;
  const int wv   = t >> 6;          // wave 0..3
  const int rbase = blockIdx.x * BM;

  const float w = width[0];
  const float s2 = (LN2F * LOG2E) / (w * w);   // p = 2^(-d2*s2)

  // ---- staging: 4x global_load_lds_dwordx4 per chunk (8KB hi + 8KB lo) ----
  auto stage = [&](int c, int buf) {
    const char* gh = (const char*)ch + (size_t)c * 8192 + wv * 1024 + lane * 16;
    const char* gl = (const char*)cl + (size_t)c * 8192 + wv * 1024 + lane * 16;
    char* lh = (char*)&Bh[buf][0] + wv * 1024;   // HW adds lane*16
    char* ll = (char*)&Bl[buf][0] + wv * 1024;
    gload16(gh,        lh);
    gload16(gh + 4096, lh + 4096);
    gload16(gl,        ll);
    gload16(gl + 4096, ll + 4096);
  };

  // issue chunk-0 staging first so it overlaps the E-table build
  stage(0, 0);

  // ---- per-axis exp tables: one thread per row ----
  if (t < BM) {
    int rr = rbase + t; if (rr >= N) rr = N - 1;
    float x0 = x[(size_t)rr * 3 + 0];
    float x1 = x[(size_t)rr * 3 + 1];
    float x2 = x[(size_t)rr * 3 + 2];
#pragma unroll
    for (int k = 0; k < 12; ++k) {
      float g = (float)k * (2.0f / 11.0f) - 1.0f;   // linspace(-1,1,12)
      float d0 = x0 - g;
      float d1 = x1 - g;
      float d2 = x2 - g;
      E0[k * BM + t] = exp2f(-d0 * d0 * s2);
      E1[k * BM + t] = exp2f(-d1 * d1 * s2);
      E2[t * 16 + k] = exp2f(-d2 * d2 * s2);
    }
#pragma unroll
    for (int k = 12; k < 16; ++k) E2[t * 16 + k] = 0.f;   // pad -> p=0
  }
  __syncthreads();   // E ready; also drains stage(0)

  const int l15  = lane & 15;
  const int g4   = lane >> 4;
  const int wvr  = wv >> 1;         // wave row group -> rows wvr*64..+64
  const int wvc  = wv & 1;          // wave col group -> cols wvc*64..+64
  const int k2b  = (g4 & 1) * 8;    // lane's fixed k2 base
  const int pairSel = g4 >> 1;

  // lane-resident e2 values: 8 per row, 4 m-subtiles
  float e2v[4][8];
#pragma unroll
  for (int mi = 0; mi < 4; ++mi) {
    int rl = wvr * 64 + mi * 16 + l15;
    f32x4 a = *(const f32x4*)&E2[rl * 16 + k2b];
    f32x4 b = *(const f32x4*)&E2[rl * 16 + k2b + 4];
    e2v[mi][0] = a.x; e2v[mi][1] = a.y; e2v[mi][2] = a.z; e2v[mi][3] = a.w;
    e2v[mi][4] = b.x; e2v[mi][5] = b.y; e2v[mi][6] = b.z; e2v[mi][7] = b.w;
  }

  f32x4 acc[4][4];
#pragma unroll
  for (int mi = 0; mi < 4; ++mi)
#pragma unroll
    for (int nn = 0; nn < 4; ++nn) acc[mi][nn] = (f32x4){0.f, 0.f, 0.f, 0.f};

  // one chunk's compute on a compile-time buffer index
  auto body = [&](int c, int buf) {
    int pair = 2 * c + pairSel;
    int i = (pair * 683) >> 13;   // /12, valid for pair<144
    int j = pair - i * 12;

    f16x8 ah[4], al[4];
#pragma unroll
    for (int mi = 0; mi < 4; ++mi) {
      int rl = wvr * 64 + mi * 16 + l15;
      float e01 = E0[i * BM + rl] * E1[j * BM + rl];
#pragma unroll
      for (int b = 0; b < 8; ++b) {
        float p = e01 * e2v[mi][b];
        f16 h = (f16)p;
        ah[mi][b] = h;
        al[mi][b] = (f16)(p - (float)h);
      }
    }

    const char* bhBase = (const char*)&Bh[buf][0];
    const char* blBase = (const char*)&Bl[buf][0];
    __builtin_amdgcn_s_setprio(1);
#pragma unroll
    for (int nn = 0; nn < 4; ++nn) {
      int off = g4 * 2048 + (wvc * 64 + nn * 16 + l15) * 16;
      f16x8 bh = *(const f16x8*)(bhBase + off);
      f16x8 bl = *(const f16x8*)(blBase + off);
#pragma unroll
      for (int mi = 0; mi < 4; ++mi) {
        acc[mi][nn] = __builtin_amdgcn_mfma_f32_16x16x32_f16(ah[mi], bh, acc[mi][nn], 0, 0, 0);
        acc[mi][nn] = __builtin_amdgcn_mfma_f32_16x16x32_f16(al[mi], bh, acc[mi][nn], 0, 0, 0);
        acc[mi][nn] = __builtin_amdgcn_mfma_f32_16x16x32_f16(ah[mi], bl, acc[mi][nn], 0, 0, 0);
      }
    }
    __builtin_amdgcn_s_setprio(0);
  };

  // main loop: sync -> issue next-chunk gload_lds -> compute current buffer.
  // Stage issued at top of iter c is consumed after the NEXT sync (iter c+1):
  // a full chunk of MFMA hides the load latency; __syncthreads' implicit
  // vmcnt(0)+barrier gives all-waves visibility of the staged buffer.
#pragma unroll 1
  for (int cc = 0; cc < CHUNKS / 2; ++cc) {
    int c0 = 2 * cc, c1 = 2 * cc + 1;
    __syncthreads();
    stage(c1, 1);
    body(c0, 0);
    __syncthreads();
    stage((c1 + 1) % CHUNKS, 0);   // last iter re-stages chunk 0: harmless
    body(c1, 1);
  }

  // epilogue: D layout col=lane&15, row=(lane>>4)*4+reg
#pragma unroll
  for (int mi = 0; mi < 4; ++mi)
#pragma unroll
    for (int nn = 0; nn < 4; ++nn)
#pragma unroll
      for (int q = 0; q < 4; ++q) {
        int row = rbase + wvr * 64 + mi * 16 + g4 * 4 + q;
        int col = wvc * 64 + nn * 16 + l15;
        if (row < N) out[(size_t)row * CD + col] = acc[mi][nn][q];
      }
}

// ---------- slow-but-correct fallback (only if ws is too small) ----------
__global__ void rbf_fallback(const float* __restrict__ x, const float* __restrict__ grid,
                             const float* __restrict__ coeffs, const float* __restrict__ width,
                             float* __restrict__ out, int N) {
  int row = blockIdx.x;
  int col = threadIdx.x;
  if (row >= N) return;
  float x0 = x[(size_t)row * 3 + 0];
  float x1 = x[(size_t)row * 3 + 1];
  float x2 = x[(size_t)row * 3 + 2];
  float w = width[0];
  float s2 = (LN2F * LOG2E) / (w * w);
  float acc = 0.f;
  for (int g = 0; g < 1728; ++g) {
    float d0 = x0 - grid[g * 3 + 0];
    float d1 = x1 - grid[g * 3 + 1];
    float d2 = x2 - grid[g * 3 + 2];
    float p = exp2f(-(d0 * d0 + d1 * d1 + d2 * d2) * s2);
    acc += p * coeffs[(size_t)g * CD + col];
  }
  out[(size_t)row * CD + col] = acc;
}

extern "C" void kernel_launch(void* const* d_in, const int* in_sizes, int n_in,
                              void* d_out, int out_size, void* d_ws, size_t ws_size,
                              hipStream_t stream) {
  const float* x      = (const float*)d_in[0];
  const float* grid   = (const float*)d_in[1];
  const float* coeffs = (const float*)d_in[2];
  const float* width  = (const float*)d_in[3];
  float* out = (float*)d_out;
  int N = in_sizes[0] / 3;

  size_t need = (size_t)2 * CD * KP * sizeof(f16);   // ~1.13 MB
  if (ws_size >= need) {
    f16* ch = (f16*)d_ws;
    f16* cl = ch + (size_t)CD * KP;
    hipLaunchKernelGGL(prep_coeffs, dim3(KP / 2), dim3(256), 0, stream,
                       coeffs, ch, cl);
    int nb = (N + BM - 1) / BM;
    hipLaunchKernelGGL(rbf_gemm, dim3(nb), dim3(256), 0, stream,
                       x, grid, width, ch, cl, out, N);
  } else {
    hipLaunchKernelGGL(rbf_fallback, dim3(N), dim3(CD), 0, stream,
                       x, grid, coeffs, width, out, N);
  }
}

// Round 4
// 321.178 us; speedup vs baseline: 1.9942x; 1.1113x over previous
//
#include <hip/hip_runtime.h>
#include <stdint.h>

// RBF_euclidean: out[N,128] = P @ coeffs, P[i,g] = exp(-d2(x_i,grid_g)*ln2/w^2)
// Round 4: same math class as round 3 (passed, absmax 0.0498), two pipe cuts:
//  - A-fragment hi/lo split via v_fma_mixlo/mixhi_f16 (2 VALU/elem vs ~6):
//      h  = f16(fma(e01, e2, 0))          (mixlo/mixhi packs for free)
//      al = f16(fma(e01, e2, -h))         (exact-product residual, op_sel reads h)
//  - 32x32x16 f16 MFMA (2178 vs 1955 TF ubench; 24 vs 48 MFMA/chunk/wave).
//    One MFMA K=16 step == one (i,j) pair (separable structure maps 1:1).
//    A: row=lane&31, k=(lane>>5)*8+b. C/D: col=lane&31, row=(q&3)+8*(q>>2)+4*(lane>>5).
//  - ws image identical to round 3 (fragment-linear); staging via global_load_lds
//    width=16, double-buffered, one barrier per chunk.

typedef _Float16 f16;
typedef _Float16 f16x8 __attribute__((ext_vector_type(8)));
typedef float f32x4 __attribute__((ext_vector_type(4)));
typedef float f32x16 __attribute__((ext_vector_type(16)));

#define LN2F 0.69314718f
#define LOG2E 1.4426950408889634f

#define KP 2304      // 12*12*16 (axis2 padded to 16)
#define CD 128       // codomain dim
#define CHUNKS 72    // KP/32
#define BM 128       // rows per block

// ---------- prep: split coeffs f16 hi/lo, emit fragment-ordered image ----------
// image layout: idx = ((kp>>3)*CD + col)*8 + (kp&7); kp = i*192 + j*16 + k2 (k2 padded to 16)
__global__ void prep_coeffs(const float* __restrict__ coeffs,
                            f16* __restrict__ ch, f16* __restrict__ cl) {
  int kp  = blockIdx.x * 2 + (threadIdx.x >> 7);   // 0..2303
  int col = threadIdx.x & 127;
  int i   = kp / 192;
  int rem = kp - i * 192;
  int j   = rem >> 4;
  int k2  = rem & 15;
  float v = 0.f;
  if (k2 < 12) v = coeffs[(size_t)((i * 12 + j) * 12 + k2) * CD + col];
  f16 h = (f16)v;
  f16 l = (f16)(v - (float)h);
  size_t idx = ((size_t)(kp >> 3) * CD + col) * 8 + (kp & 7);
  ch[idx] = h;
  cl[idx] = l;
}

__device__ __forceinline__ void gload16(const void* g, void* l) {
  __builtin_amdgcn_global_load_lds(
      (const __attribute__((address_space(1))) void*)g,
      (__attribute__((address_space(3))) void*)l, 16, 0, 0);
}

union FU { uint32_t u[4]; f16x8 v; };

// ---------- main GEMM ----------
__global__ __launch_bounds__(256) void rbf_gemm(
    const float* __restrict__ x,
    const float* __restrict__ width,
    const f16* __restrict__ ch, const f16* __restrict__ cl,
    float* __restrict__ out, int N) {
  __shared__ float E0[12 * BM];    // 6 KB
  __shared__ float E1[12 * BM];    // 6 KB
  __shared__ float E2[BM * 16];    // 8 KB
  __shared__ f16 Bh[2][32 * CD];   // 16 KB (linear fragment image, dbuf)
  __shared__ f16 Bl[2][32 * CD];   // 16 KB

  const int t = threadIdx.x;
  const int lane = t & 63;
  const int wv   = t >> 6;          // wave 0..3
  const int rbase = blockIdx.x * BM;

  const float w = width[0];
  const float s2 = (LN2F * LOG2E) / (w * w);   // p = 2^(-d2*s2)

  // ---- staging: 4x global_load_lds_dwordx4 per chunk (8KB hi + 8KB lo) ----
  auto stage = [&](int c, int buf) {
    const char* gh = (const char*)ch + (size_t)c * 8192 + wv * 1024 + lane * 16;
    const char* gl = (const char*)cl + (size_t)c * 8192 + wv * 1024 + lane * 16;
    char* lh = (char*)&Bh[buf][0] + wv * 1024;   // HW adds lane*16
    char* ll = (char*)&Bl[buf][0] + wv * 1024;
    gload16(gh,        lh);
    gload16(gh + 4096, lh + 4096);
    gload16(gl,        ll);
    gload16(gl + 4096, ll + 4096);
  };

  // issue chunk-0 staging first so it overlaps the E-table build
  stage(0, 0);

  // ---- per-axis exp tables: one thread per row ----
  if (t < BM) {
    int rr = rbase + t; if (rr >= N) rr = N - 1;
    float x0 = x[(size_t)rr * 3 + 0];
    float x1 = x[(size_t)rr * 3 + 1];
    float x2 = x[(size_t)rr * 3 + 2];
#pragma unroll
    for (int k = 0; k < 12; ++k) {
      float g = (float)k * (2.0f / 11.0f) - 1.0f;   // linspace(-1,1,12)
      float d0 = x0 - g;
      float d1 = x1 - g;
      float d2 = x2 - g;
      E0[k * BM + t] = __builtin_amdgcn_exp2f(-d0 * d0 * s2);
      E1[k * BM + t] = __builtin_amdgcn_exp2f(-d1 * d1 * s2);
      E2[t * 16 + k] = __builtin_amdgcn_exp2f(-d2 * d2 * s2);
    }
#pragma unroll
    for (int k = 12; k < 16; ++k) E2[t * 16 + k] = 0.f;   // pad -> p=0
  }
  __syncthreads();   // E ready; also drains stage(0)

  const int l31 = lane & 31;
  const int hh  = lane >> 5;        // k-half within a pair's 16-K block
  const int wvr = wv >> 1;          // wave row group -> rows wvr*64..+64
  const int wvc = wv & 1;           // wave col group -> cols wvc*64..+64

  // lane-resident e2 values: 8 per row (k2 = hh*8 + b), 2 m-subtiles of 32 rows
  float e2v[2][8];
#pragma unroll
  for (int mi = 0; mi < 2; ++mi) {
    int rl = wvr * 64 + mi * 32 + l31;
    f32x4 a = *(const f32x4*)&E2[rl * 16 + hh * 8];
    f32x4 b = *(const f32x4*)&E2[rl * 16 + hh * 8 + 4];
    e2v[mi][0] = a.x; e2v[mi][1] = a.y; e2v[mi][2] = a.z; e2v[mi][3] = a.w;
    e2v[mi][4] = b.x; e2v[mi][5] = b.y; e2v[mi][6] = b.z; e2v[mi][7] = b.w;
  }

  f32x16 acc[2][2];
  {
    f32x16 z;
#pragma unroll
    for (int q = 0; q < 16; ++q) z[q] = 0.f;
#pragma unroll
    for (int mi = 0; mi < 2; ++mi)
#pragma unroll
      for (int nn = 0; nn < 2; ++nn) acc[mi][nn] = z;
  }

  // one chunk's compute on a compile-time buffer index
  auto body = [&](int c, int buf) {
    int p0 = 2 * c, p1 = p0 + 1;
    int i0 = (p0 * 683) >> 13, j0 = p0 - i0 * 12;   // /12, valid for pair<144
    int i1 = (p1 * 683) >> 13, j1 = p1 - i1 * 12;
    const char* bhBase = (const char*)&Bh[buf][0];
    const char* blBase = (const char*)&Bl[buf][0];

#pragma unroll
    for (int s = 0; s < 2; ++s) {        // s = pair index within chunk
      int ii = s ? i1 : i0;
      int jj = s ? j1 : j0;

      // B fragments for this pair: [(s*2+hh)][col][b] image
      f16x8 bh[2], bl[2];
#pragma unroll
      for (int nn = 0; nn < 2; ++nn) {
        int off = ((s * 2 + hh) * 128 + wvc * 64 + nn * 32 + l31) * 16;
        bh[nn] = *(const f16x8*)(bhBase + off);
        bl[nn] = *(const f16x8*)(blBase + off);
      }

      // A fragments: p = e01*e2, hi/lo via v_fma_mix (2 VALU per element)
      FU ah[2], al[2];
#pragma unroll
      for (int mi = 0; mi < 2; ++mi) {
        int rl = wvr * 64 + mi * 32 + l31;
        float e01 = E0[ii * BM + rl] * E1[jj * BM + rl];
#pragma unroll
        for (int q = 0; q < 4; ++q) {
          float ea = e2v[mi][2 * q];
          float eb = e2v[mi][2 * q + 1];
          uint32_t hq, lq;
          asm("v_fma_mixlo_f16 %0, %1, %2, 0"
              : "=v"(hq) : "v"(e01), "v"(ea));
          asm("v_fma_mixhi_f16 %0, %1, %2, 0"
              : "+v"(hq) : "v"(e01), "v"(eb));
          asm("v_fma_mixlo_f16 %0, %1, %2, -%3 op_sel:[0,0,0] op_sel_hi:[0,0,1]"
              : "=v"(lq) : "v"(e01), "v"(ea), "v"(hq));
          asm("v_fma_mixhi_f16 %0, %1, %2, -%3 op_sel:[0,0,1] op_sel_hi:[0,0,1]"
              : "+v"(lq) : "v"(e01), "v"(eb), "v"(hq));
          ah[mi].u[q] = hq;
          al[mi].u[q] = lq;
        }
      }

      __builtin_amdgcn_s_setprio(1);
#pragma unroll
      for (int nn = 0; nn < 2; ++nn)
#pragma unroll
        for (int mi = 0; mi < 2; ++mi)
          acc[mi][nn] = __builtin_amdgcn_mfma_f32_32x32x16_f16(ah[mi].v, bh[nn], acc[mi][nn], 0, 0, 0);
#pragma unroll
      for (int nn = 0; nn < 2; ++nn)
#pragma unroll
        for (int mi = 0; mi < 2; ++mi)
          acc[mi][nn] = __builtin_amdgcn_mfma_f32_32x32x16_f16(al[mi].v, bh[nn], acc[mi][nn], 0, 0, 0);
#pragma unroll
      for (int nn = 0; nn < 2; ++nn)
#pragma unroll
        for (int mi = 0; mi < 2; ++mi)
          acc[mi][nn] = __builtin_amdgcn_mfma_f32_32x32x16_f16(ah[mi].v, bl[nn], acc[mi][nn], 0, 0, 0);
      __builtin_amdgcn_s_setprio(0);
    }
  };

  // main loop: sync -> issue next-chunk gload_lds -> compute current buffer.
#pragma unroll 1
  for (int cc = 0; cc < CHUNKS / 2; ++cc) {
    int c0 = 2 * cc, c1 = 2 * cc + 1;
    __syncthreads();
    stage(c1, 1);
    body(c0, 0);
    __syncthreads();
    stage((c1 + 1) % CHUNKS, 0);   // last iter re-stages chunk 0: harmless
    body(c1, 1);
  }

  // epilogue: 32x32 D layout: col=lane&31, row=(q&3)+8*(q>>2)+4*(lane>>5)
#pragma unroll
  for (int mi = 0; mi < 2; ++mi)
#pragma unroll
    for (int nn = 0; nn < 2; ++nn)
#pragma unroll
      for (int q = 0; q < 16; ++q) {
        int row = rbase + wvr * 64 + mi * 32 + (q & 3) + 8 * (q >> 2) + 4 * hh;
        int col = wvc * 64 + nn * 32 + l31;
        if (row < N) out[(size_t)row * CD + col] = acc[mi][nn][q];
      }
}

// ---------- slow-but-correct fallback (only if ws is too small) ----------
__global__ void rbf_fallback(const float* __restrict__ x, const float* __restrict__ grid,
                             const float* __restrict__ coeffs, const float* __restrict__ width,
                             float* __restrict__ out, int N) {
  int row = blockIdx.x;
  int col = threadIdx.x;
  if (row >= N) return;
  float x0 = x[(size_t)row * 3 + 0];
  float x1 = x[(size_t)row * 3 + 1];
  float x2 = x[(size_t)row * 3 + 2];
  float w = width[0];
  float s2 = (LN2F * LOG2E) / (w * w);
  float acc = 0.f;
  for (int g = 0; g < 1728; ++g) {
    float d0 = x0 - grid[g * 3 + 0];
    float d1 = x1 - grid[g * 3 + 1];
    float d2 = x2 - grid[g * 3 + 2];
    float p = exp2f(-(d0 * d0 + d1 * d1 + d2 * d2) * s2);
    acc += p * coeffs[(size_t)g * CD + col];
  }
  out[(size_t)row * CD + col] = acc;
}

extern "C" void kernel_launch(void* const* d_in, const int* in_sizes, int n_in,
                              void* d_out, int out_size, void* d_ws, size_t ws_size,
                              hipStream_t stream) {
  const float* x      = (const float*)d_in[0];
  const float* grid   = (const float*)d_in[1];
  const float* coeffs = (const float*)d_in[2];
  const float* width  = (const float*)d_in[3];
  float* out = (float*)d_out;
  int N = in_sizes[0] / 3;

  size_t need = (size_t)2 * CD * KP * sizeof(f16);   // ~1.13 MB
  if (ws_size >= need) {
    f16* ch = (f16*)d_ws;
    f16* cl = ch + (size_t)CD * KP;
    hipLaunchKernelGGL(prep_coeffs, dim3(KP / 2), dim3(256), 0, stream,
                       coeffs, ch, cl);
    int nb = (N + BM - 1) / BM;
    hipLaunchKernelGGL(rbf_gemm, dim3(nb), dim3(256), 0, stream,
                       x, width, ch, cl, out, N);
  } else {
    hipLaunchKernelGGL(rbf_fallback, dim3(N), dim3(CD), 0, stream,
                       x, grid, coeffs, width, out, N);
  }
}